// Round 9
// baseline (164.132 us; speedup 1.0000x reference)
//
#include <hip/hip_runtime.h>
#include <hip/hip_bf16.h>

// HyperbolicMessagePassing: N=50000, E=600000, D=128.
// out = expmap0( MLP2( mean_scatter( MLP1(logmap0(x))[src] -> dst ) ) )
// Message MLP depends only on src -> compute per-node (50k rows not 600k).
// R18 = R17 base (155.6us: fused fill+MLP stage1, 1-wave stage2) +
// deep-pipelined stage2 gather:
//   R17 stage2 processed its 4 rows serially, each a 3-round-trip chain
//   (deg -> window -> 16 gathers): ~16 loads in flight. If latency-bound,
//   depth is the lever: hoist all 4 rows' metadata upfront (12 parallel
//   loads) and issue gathers 2 rows at a time (32 in flight).

#define DD 128
#define CAP 64   // padded-CSR slots per node
#define DS 16    // degv stride in ints (64B line per counter)

typedef __attribute__((ext_vector_type(8))) short short8;
typedef __attribute__((ext_vector_type(8))) unsigned short u16x8;
typedef __attribute__((ext_vector_type(4))) unsigned short u16x4;
typedef __attribute__((ext_vector_type(4))) float f32x4;

__device__ __forceinline__ unsigned short f2bf(float f) {
  unsigned u = __float_as_uint(f);
  u += 0x7fffu + ((u >> 16) & 1u);  // round-to-nearest-even
  return (unsigned short)(u >> 16);
}
__device__ __forceinline__ float bf2f(short h) {
  return __uint_as_float(((unsigned)(unsigned short)h) << 16);
}

// blocks [0,32): pack 4 W (fp32 128x128) into bf16 MFMA B-frag-linear order:
//   P[m*16384 + ((cc*4+s)*64 + lane)*8 + j]
//     = bf16(W[(s*32+(lane>>4)*8+j)*128 + cc*16+(lane&15)])
// blocks [32,..): zero degv[N] (padded stride DS)
__global__ void k_init(const float* __restrict__ w1, const float* __restrict__ w2,
                       const float* __restrict__ w3, const float* __restrict__ w4,
                       unsigned short* __restrict__ P, int* __restrict__ degv, int N) {
  if (blockIdx.x < 32) {
    int idx = blockIdx.x * 256 + threadIdx.x;  // 4 matrices x 2048 (frag,lane)
    int m = idx >> 11;
    int id = idx & 2047;
    int f = id >> 6, l = id & 63;
    int cc = f >> 2, s = f & 3, q = l >> 4, n15 = l & 15;
    const float* W = (m == 0) ? w1 : (m == 1) ? w2 : (m == 2) ? w3 : w4;
    const float* wp = W + (s * 32 + q * 8) * DD + cc * 16 + n15;
    unsigned short* op = P + (size_t)m * 16384 + (size_t)id * 8;
#pragma unroll
    for (int j = 0; j < 8; ++j) op[j] = f2bf(wp[j * DD]);
  } else {
    int i = (blockIdx.x - 32) * 256 + threadIdx.x;
    if (i < N) degv[(size_t)i * DS] = 0;
  }
}

// stage1: blocks [0,ne) = padded-CSR edge fill, 4 edges/thread (dispatched
//         FIRST, overlaps MLP); blocks [ne,..) = logmap0 + MLP1 -> node_msg.
// 256 threads = 4 waves. Wave wv: rt=wv>>1 (16 rows), ct=wv&1 (64 cols).
__global__ __launch_bounds__(256) void k_stage1(
    const float* __restrict__ x, const int* __restrict__ ei,
    const unsigned short* __restrict__ Pa, const float* __restrict__ ba,
    const unsigned short* __restrict__ Pb, const float* __restrict__ bb,
    unsigned short* __restrict__ node_msg, int* __restrict__ degv,
    unsigned short* __restrict__ ebuf, int N, int E, int ne) {
  __shared__ unsigned short As[32 * 136];  // row stride 136 shorts
  const int tid = threadIdx.x;

  if (blockIdx.x < ne) {  // ---- edge-fill: 1024 edges/block, 4/thread ----
    int eb_[4], d_[4], s_[4], p_[4];
#pragma unroll
    for (int k = 0; k < 4; ++k) {
      int e = blockIdx.x * 1024 + k * 256 + tid;
      eb_[k] = e;
      if (e < E) {
        d_[k] = ei[e];       // edge_index[0] = dst
        s_[k] = ei[E + e];   // edge_index[1] = src
      }
    }
#pragma unroll
    for (int k = 0; k < 4; ++k)
      if (eb_[k] < E) p_[k] = atomicAdd(degv + (size_t)d_[k] * DS, 1);
#pragma unroll
    for (int k = 0; k < 4; ++k)
      if (eb_[k] < E && p_[k] < CAP)
        ebuf[(size_t)d_[k] * CAP + p_[k]] = (unsigned short)s_[k];
    return;
  }

  const int lane = tid & 63;
  const int wv = tid >> 6;  // 0..3
  const int rt = wv >> 1;   // row-tile 0..1
  const int ct = wv & 1;    // col-tile 0..1
  const int q = lane >> 4;
  const int n15 = lane & 15;
  const int row0 = (blockIdx.x - ne) * 32;
  const int g = (wv << 2) | q;  // staging group 0..15

  // ---- stage A tile: logmap0, group g rows g*2..g*2+1, 16 lanes/row ----
  f32x4 xa[2][2];
#pragma unroll
  for (int i = 0; i < 2; ++i) {
    const int grow = row0 + g * 2 + i;
    if (grow < N) {
      const f32x4* p = (const f32x4*)(x + (size_t)grow * DD + n15 * 8);
      xa[i][0] = p[0];
      xa[i][1] = p[1];
    } else {
      xa[i][0] = (f32x4){0.f, 0.f, 0.f, 0.f};
      xa[i][1] = (f32x4){0.f, 0.f, 0.f, 0.f};
    }
  }
#pragma unroll
  for (int i = 0; i < 2; ++i) {
    const int r = g * 2 + i;
    f32x4 s0 = xa[i][0], s1 = xa[i][1];
    float ss = s0[0]*s0[0] + s0[1]*s0[1] + s0[2]*s0[2] + s0[3]*s0[3]
             + s1[0]*s1[0] + s1[1]*s1[1] + s1[2]*s1[2] + s1[3]*s1[3];
    ss += __shfl_xor(ss, 1);
    ss += __shfl_xor(ss, 2);
    ss += __shfl_xor(ss, 4);
    ss += __shfl_xor(ss, 8);
    float nrm = sqrtf(ss);
    float nc = fminf(fmaxf(nrm, 1e-8f), 1.0f - 1e-5f);
    float sc = atanhf(nc) / nc;
    s0 *= sc;
    s1 *= sc;
    uint4 pk;
    pk.x = (unsigned)f2bf(s0[0]) | ((unsigned)f2bf(s0[1]) << 16);
    pk.y = (unsigned)f2bf(s0[2]) | ((unsigned)f2bf(s0[3]) << 16);
    pk.z = (unsigned)f2bf(s1[0]) | ((unsigned)f2bf(s1[1]) << 16);
    pk.w = (unsigned)f2bf(s1[2]) | ((unsigned)f2bf(s1[3]) << 16);
    *(uint4*)((unsigned*)As + r * 68 + n15 * 4) = pk;
  }
  __syncthreads();

  // ---- layer 1 ----
  float bc[4];
#pragma unroll
  for (int c = 0; c < 4; ++c) bc[c] = ba[ct * 64 + c * 16 + n15];
  f32x4 acc[4];
#pragma unroll
  for (int c = 0; c < 4; ++c) acc[c] = (f32x4){0.f, 0.f, 0.f, 0.f};
  const int abase = (rt * 16 + n15) * 136 + q * 8;  // A[m=n15][k=q*8+j]
  short8 bfr[16];
#pragma unroll
  for (int s = 0; s < 4; ++s)
#pragma unroll
    for (int c = 0; c < 4; ++c)
      bfr[s * 4 + c] =
          *(const short8*)&Pa[(size_t)(((((ct << 2) | c) << 2) | s) * 64 + lane) * 8];
  short8 afr[4];
#pragma unroll
  for (int s = 0; s < 4; ++s) afr[s] = *(const short8*)&As[abase + s * 32];
#pragma unroll
  for (int s = 0; s < 4; ++s)
#pragma unroll
    for (int c = 0; c < 4; ++c)
      acc[c] = __builtin_amdgcn_mfma_f32_16x16x32_bf16(afr[s], bfr[s * 4 + c],
                                                       acc[c], 0, 0, 0);
  __syncthreads();

  // relu + bias -> As (C/D: row = rt*16 + q*4 + rr, col = ct*64 + c*16 + n15)
#pragma unroll
  for (int c = 0; c < 4; ++c)
#pragma unroll
    for (int rr = 0; rr < 4; ++rr) {
      float v = fmaxf(acc[c][rr] + bc[c], 0.f);
      As[(rt * 16 + q * 4 + rr) * 136 + ct * 64 + c * 16 + n15] = f2bf(v);
    }
  __syncthreads();

  // ---- layer 2 ----
#pragma unroll
  for (int c = 0; c < 4; ++c) bc[c] = bb[ct * 64 + c * 16 + n15];
#pragma unroll
  for (int c = 0; c < 4; ++c) acc[c] = (f32x4){0.f, 0.f, 0.f, 0.f};
#pragma unroll
  for (int s = 0; s < 4; ++s)
#pragma unroll
    for (int c = 0; c < 4; ++c)
      bfr[s * 4 + c] =
          *(const short8*)&Pb[(size_t)(((((ct << 2) | c) << 2) | s) * 64 + lane) * 8];
#pragma unroll
  for (int s = 0; s < 4; ++s) afr[s] = *(const short8*)&As[abase + s * 32];
#pragma unroll
  for (int s = 0; s < 4; ++s)
#pragma unroll
    for (int c = 0; c < 4; ++c)
      acc[c] = __builtin_amdgcn_mfma_f32_16x16x32_bf16(afr[s], bfr[s * 4 + c],
                                                       acc[c], 0, 0, 0);

  // write bf16 node_msg via LDS repack -> coalesced 16B stores
  __syncthreads();
#pragma unroll
  for (int c = 0; c < 4; ++c)
#pragma unroll
    for (int rr = 0; rr < 4; ++rr)
      As[(rt * 16 + q * 4 + rr) * 136 + ct * 64 + c * 16 + n15] =
          f2bf(acc[c][rr] + bc[c]);
  __syncthreads();
#pragma unroll
  for (int k = 0; k < 2; ++k) {  // 32 rows x 16 chunks = 512 units / 256 thr
    int u = tid + k * 256;
    int r = u >> 4, ch = u & 15;
    int grow = row0 + r;
    if (grow < N)
      *(short8*)(node_msg + (size_t)grow * DD + ch * 8) =
          *(const short8*)&As[r * 136 + ch * 8];
  }
}

// stage2: 1 wave / 16 rows / block. Deep-pipelined gather + mean -> MLP2 ->
// expmap0 -> out. lane: q=lane>>4 (rows q*4..q*4+3), n15=lane&15 (col chunk).
__global__ __launch_bounds__(64) void k_stage2(
    const unsigned short* __restrict__ node_msg, const int* __restrict__ degv,
    const unsigned short* __restrict__ ebuf, const unsigned short* __restrict__ Pa,
    const float* __restrict__ ba, const unsigned short* __restrict__ Pb,
    const float* __restrict__ bb, float* __restrict__ out, int N) {
  __shared__ unsigned short As[16 * 136];
  const int lane = threadIdx.x;  // 0..63
  const int q = lane >> 4;
  const int n15 = lane & 15;
  const int row0 = blockIdx.x * 16;

  // ---- hoist ALL 4 rows' metadata upfront: 12 parallel loads ----
  int d4[4];
  u16x8 wA[4], wB[4];
#pragma unroll
  for (int i = 0; i < 4; ++i) {
    const int grow = row0 + q * 4 + i;
    if (grow < N) {
      d4[i] = degv[(size_t)grow * DS];
      const unsigned short* eb = ebuf + (size_t)grow * CAP;
      wA[i] = *(const u16x8*)(eb);
      wB[i] = *(const u16x8*)(eb + 8);
    } else {
      d4[i] = 0;
      wA[i] = (u16x8){0, 0, 0, 0, 0, 0, 0, 0};
      wB[i] = (u16x8){0, 0, 0, 0, 0, 0, 0, 0};
    }
  }

  // ---- gather + mean: rows in PAIRS, 32 gathers in flight per pair ----
#pragma unroll
  for (int pp = 0; pp < 2; ++pp) {
    const int iA = pp * 2, iB = pp * 2 + 1;
    const int dlA = (d4[iA] < CAP) ? d4[iA] : CAP;
    const int dlB = (d4[iB] < CAP) ? d4[iB] : CAP;
    short8 vA[16], vB[16];
#pragma unroll
    for (int t = 0; t < 8; ++t) {
      int sA0 = (t < dlA) ? (int)wA[iA][t] : 0;       // poison -> safe row 0
      int sA1 = (t + 8 < dlA) ? (int)wB[iA][t] : 0;
      int sB0 = (t < dlB) ? (int)wA[iB][t] : 0;
      int sB1 = (t + 8 < dlB) ? (int)wB[iB][t] : 0;
      vA[t] = *(const short8*)(node_msg + (size_t)sA0 * DD + n15 * 8);
      vA[t + 8] = *(const short8*)(node_msg + (size_t)sA1 * DD + n15 * 8);
      vB[t] = *(const short8*)(node_msg + (size_t)sB0 * DD + n15 * 8);
      vB[t + 8] = *(const short8*)(node_msg + (size_t)sB1 * DD + n15 * 8);
    }
    // accumulate + finish row A, then row B (B's loads still landing)
#pragma unroll
    for (int w2 = 0; w2 < 2; ++w2) {
      const int ir = (w2 == 0) ? iA : iB;
      const int dl = (w2 == 0) ? dlA : dlB;
      f32x4 s0 = {0.f, 0.f, 0.f, 0.f}, s1 = {0.f, 0.f, 0.f, 0.f};
      f32x4 t0 = {0.f, 0.f, 0.f, 0.f}, t1 = {0.f, 0.f, 0.f, 0.f};
#pragma unroll
      for (int t = 0; t < 16; ++t) {
        const short8 vv = (w2 == 0) ? vA[t] : vB[t];
        if (t < dl) {
#pragma unroll
          for (int j = 0; j < 4; ++j) {
            if (t & 1) {
              t0[j] += bf2f(vv[j]);
              t1[j] += bf2f(vv[j + 4]);
            } else {
              s0[j] += bf2f(vv[j]);
              s1[j] += bf2f(vv[j + 4]);
            }
          }
        }
      }
      // tail: deg > 16 (~10% of rows), 4-deep
      const int grow = row0 + q * 4 + ir;
      if (dl > 16) {
        const unsigned short* eb = ebuf + (size_t)grow * CAP;
        int t = 16;
        for (; t + 3 < dl; t += 4) {
          u16x4 idx = *(const u16x4*)(eb + t);
          short8 v0 = *(const short8*)(node_msg + (size_t)idx[0] * DD + n15 * 8);
          short8 v1 = *(const short8*)(node_msg + (size_t)idx[1] * DD + n15 * 8);
          short8 v2 = *(const short8*)(node_msg + (size_t)idx[2] * DD + n15 * 8);
          short8 v3 = *(const short8*)(node_msg + (size_t)idx[3] * DD + n15 * 8);
#pragma unroll
          for (int j = 0; j < 4; ++j) {
            s0[j] += bf2f(v0[j]) + bf2f(v1[j]);
            s1[j] += bf2f(v0[j + 4]) + bf2f(v1[j + 4]);
            t0[j] += bf2f(v2[j]) + bf2f(v3[j]);
            t1[j] += bf2f(v2[j + 4]) + bf2f(v3[j + 4]);
          }
        }
        for (; t < dl; ++t) {
          int sa = eb[t];
          short8 va = *(const short8*)(node_msg + (size_t)sa * DD + n15 * 8);
#pragma unroll
          for (int j = 0; j < 4; ++j) {
            s0[j] += bf2f(va[j]);
            s1[j] += bf2f(va[j + 4]);
          }
        }
      }
      s0 += t0;
      s1 += t1;
      float inv = 1.f / ((float)d4[ir] + 1e-8f);  // mean (count + EPS)
      s0 *= inv;
      s1 *= inv;
      uint4 pk;
      pk.x = (unsigned)f2bf(s0[0]) | ((unsigned)f2bf(s0[1]) << 16);
      pk.y = (unsigned)f2bf(s0[2]) | ((unsigned)f2bf(s0[3]) << 16);
      pk.z = (unsigned)f2bf(s1[0]) | ((unsigned)f2bf(s1[1]) << 16);
      pk.w = (unsigned)f2bf(s1[2]) | ((unsigned)f2bf(s1[3]) << 16);
      *(uint4*)((unsigned*)As + (q * 4 + ir) * 68 + n15 * 4) = pk;
    }
  }
  __syncthreads();  // single wave: cheap s_barrier + waitcnt

  // ---- layer 1: 16 rows x 128 cols in one wave (8 col-frags) ----
  float bc[8];
#pragma unroll
  for (int cc = 0; cc < 8; ++cc) bc[cc] = ba[cc * 16 + n15];
  f32x4 acc[8];
#pragma unroll
  for (int cc = 0; cc < 8; ++cc) acc[cc] = (f32x4){0.f, 0.f, 0.f, 0.f};
  const int abase = n15 * 136 + q * 8;  // A[row=n15][k=q*8+j]
  short8 afr[4];
#pragma unroll
  for (int s = 0; s < 4; ++s) afr[s] = *(const short8*)&As[abase + s * 32];
#pragma unroll
  for (int s = 0; s < 4; ++s)
#pragma unroll
    for (int cc = 0; cc < 8; ++cc) {
      short8 b = *(const short8*)&Pa[(size_t)((cc * 4 + s) * 64 + lane) * 8];
      acc[cc] = __builtin_amdgcn_mfma_f32_16x16x32_bf16(afr[s], b, acc[cc], 0, 0, 0);
    }
  __syncthreads();

  // relu + bias -> As (C/D: row = q*4 + rr, col = cc*16 + n15)
#pragma unroll
  for (int cc = 0; cc < 8; ++cc)
#pragma unroll
    for (int rr = 0; rr < 4; ++rr) {
      float v = fmaxf(acc[cc][rr] + bc[cc], 0.f);
      As[(q * 4 + rr) * 136 + cc * 16 + n15] = f2bf(v);
    }
  __syncthreads();

  // ---- layer 2 ----
#pragma unroll
  for (int cc = 0; cc < 8; ++cc) bc[cc] = bb[cc * 16 + n15];
#pragma unroll
  for (int cc = 0; cc < 8; ++cc) acc[cc] = (f32x4){0.f, 0.f, 0.f, 0.f};
#pragma unroll
  for (int s = 0; s < 4; ++s) afr[s] = *(const short8*)&As[abase + s * 32];
#pragma unroll
  for (int s = 0; s < 4; ++s)
#pragma unroll
    for (int cc = 0; cc < 8; ++cc) {
      short8 b = *(const short8*)&Pb[(size_t)((cc * 4 + s) * 64 + lane) * 8];
      acc[cc] = __builtin_amdgcn_mfma_f32_16x16x32_bf16(afr[s], b, acc[cc], 0, 0, 0);
    }

  // ---- expmap0 epilogue: row q*4+rr fully within this 16-lane group ----
#pragma unroll
  for (int rr = 0; rr < 4; ++rr) {
    float vv[8];
    float ssq = 0.f;
#pragma unroll
    for (int cc = 0; cc < 8; ++cc) {
      vv[cc] = acc[cc][rr] + bc[cc];
      ssq += vv[cc] * vv[cc];
    }
    ssq += __shfl_xor(ssq, 1);
    ssq += __shfl_xor(ssq, 2);
    ssq += __shfl_xor(ssq, 4);
    ssq += __shfl_xor(ssq, 8);
    float nrm = sqrtf(ssq);
    float nc = fmaxf(nrm, 1e-8f);
    float sc = tanhf(nc) / nc;
    int grow = row0 + q * 4 + rr;
    if (grow < N) {
#pragma unroll
      for (int cc = 0; cc < 8; ++cc)
        __builtin_nontemporal_store(
            vv[cc] * sc, out + (size_t)grow * DD + cc * 16 + n15);
    }
  }
}

extern "C" void kernel_launch(void* const* d_in, const int* in_sizes, int n_in,
                              void* d_out, int out_size, void* d_ws, size_t ws_size,
                              hipStream_t stream) {
  const float* x = (const float*)d_in[0];
  const int* ei = (const int*)d_in[1];
  const float* w1 = (const float*)d_in[2];
  const float* b1 = (const float*)d_in[3];
  const float* w2 = (const float*)d_in[4];
  const float* b2 = (const float*)d_in[5];
  const float* w3 = (const float*)d_in[6];
  const float* b3 = (const float*)d_in[7];
  const float* w4 = (const float*)d_in[8];
  const float* b4 = (const float*)d_in[9];
  const int N = in_sizes[0] / DD;
  const int E = in_sizes[1] / 2;
  const int nf = (N + 31) / 32;
  const int nf2 = (N + 15) / 16;
  const int ne = (E + 1023) / 1024;  // 4 edges/thread, 1024/block

  // ws carve: node_msg[N*128 bf16] | degv[N*16 int, 64B-padded] |
  //           ebuf[N*64 u16] | P[4*16384 bf16]   (~22.5 MB total)
  unsigned short* node_msg = (unsigned short*)d_ws;
  int* degv = (int*)(node_msg + (size_t)N * DD);
  unsigned short* ebuf = (unsigned short*)(degv + (size_t)N * DS);
  uintptr_t pw = (uintptr_t)(ebuf + (size_t)N * CAP);
  pw = (pw + 63) & ~(uintptr_t)63;
  unsigned short* P = (unsigned short*)pw;
  float* outp = (float*)d_out;

  hipLaunchKernelGGL(k_init, dim3(32 + (N + 255) / 256), dim3(256), 0, stream,
                     w1, w2, w3, w4, P, degv, N);
  hipLaunchKernelGGL(k_stage1, dim3(ne + nf), dim3(256), 0, stream,
                     x, ei, P, b1, P + 16384, b2, node_msg, degv, ebuf, N, E, ne);
  hipLaunchKernelGGL(k_stage2, dim3(nf2), dim3(64), 0, stream,
                     node_msg, degv, ebuf, P + 2 * 16384, b3, P + 3 * 16384, b4,
                     outp, N);
}